// Round 8
// baseline (423.759 us; speedup 1.0000x reference)
//
#include <hip/hip_runtime.h>
#include <hip/hip_bf16.h>
#include <stdint.h>

// Problem constants (from reference setup_inputs)
#define BB 64
#define SS 2048
#define DD 6
#define HH 8
#define NCH 512           // chains = B*H
#define CHUNKS 512        // chunks per chain
#define LCH 4             // steps per chunk = SS/CHUNKS
// WORKSPACE CEILING: 80 MB (round 6 at 96 MB OOB-stomped). This round uses 32 MB.

typedef unsigned short ushort_t;
typedef __attribute__((ext_vector_type(8))) __bf16 bf16x8;
typedef __attribute__((ext_vector_type(4))) float f32x4;

// ---------------- compile-time Cayley sign table (Cl(4,1)) ----------------
struct SignTab { float s[32][32]; };

constexpr int popc5_c(unsigned v) {
    int c = 0;
    for (int i = 0; i < 5; ++i) c += (v >> i) & 1u;
    return c;
}

constexpr SignTab make_signs() {
    SignTab t{};
    for (int a = 0; a < 32; ++a) {
        for (int b = 0; b < 32; ++b) {
            int cnt = 0;
            unsigned aa = ((unsigned)a) >> 1;
            while (aa) { cnt += popc5_c(aa & (unsigned)b); aa >>= 1; }
            if ((a & b) & 16) cnt += 1;   // metric: e5^2 = -1 (bit 4)
            t.s[a][b] = (cnt & 1) ? -1.0f : 1.0f;
        }
    }
    return t;
}

constexpr SignTab SGN = make_signs();

// out = a * b  (geometric product, a is LEFT operand: out_k = sum_i s(i,i^k) a_i b_{i^k})
__device__ __forceinline__ void gp_cl41(const float* __restrict__ a,
                                        const float* __restrict__ b,
                                        float* __restrict__ o) {
#pragma unroll
    for (int k = 0; k < 32; ++k) o[k] = 0.0f;
#pragma unroll
    for (int i = 0; i < 32; ++i) {
#pragma unroll
        for (int k = 0; k < 32; ++k) {
            o[k] = fmaf(SGN.s[i][i ^ k] * a[i], b[i ^ k], o[k]);
        }
    }
}

__device__ __forceinline__ float sumsq32(const float* v) {
    float n0 = 0.f, n1 = 0.f, n2 = 0.f, n3 = 0.f;
#pragma unroll
    for (int k = 0; k < 32; k += 4) {
        n0 = fmaf(v[k+0], v[k+0], n0);
        n1 = fmaf(v[k+1], v[k+1], n1);
        n2 = fmaf(v[k+2], v[k+2], n2);
        n3 = fmaf(v[k+3], v[k+3], n3);
    }
    return (n0 + n1) + (n2 + n3);
}

__device__ __forceinline__ float rsq(float n) {
    return __builtin_amdgcn_rsqf(n);   // v_rsq_f32, scale-equivalent
}

__device__ __forceinline__ uint32_t f2bf_rne(float f) {
    uint32_t u = __float_as_uint(f);
    return (u + 0x7FFFu + ((u >> 16) & 1u)) >> 16;
}

// delta for two consecutive steps from one W sweep (sW4 layout: [h][d*8+j4]=W, [h][48..55]=bias)
__device__ __forceinline__ void delta_pair(const float4 (*sW4)[57], int h,
                                           const float* x0, const float* x1,
                                           float* dl0, float* dl1) {
#pragma unroll
    for (int j4 = 0; j4 < 8; ++j4) {
        float4 bv = sW4[h][48 + j4];
        dl0[4*j4+0] = bv.x; dl0[4*j4+1] = bv.y; dl0[4*j4+2] = bv.z; dl0[4*j4+3] = bv.w;
        dl1[4*j4+0] = bv.x; dl1[4*j4+1] = bv.y; dl1[4*j4+2] = bv.z; dl1[4*j4+3] = bv.w;
    }
#pragma unroll
    for (int d = 0; d < 6; ++d) {
        float a0 = x0[d], a1 = x1[d];
#pragma unroll
        for (int j4 = 0; j4 < 8; ++j4) {
            float4 w = sW4[h][d * 8 + j4];   // one LDS read serves both steps
            dl0[4*j4+0] = fmaf(a0, w.x, dl0[4*j4+0]);
            dl0[4*j4+1] = fmaf(a0, w.y, dl0[4*j4+1]);
            dl0[4*j4+2] = fmaf(a0, w.z, dl0[4*j4+2]);
            dl0[4*j4+3] = fmaf(a0, w.w, dl0[4*j4+3]);
            dl1[4*j4+0] = fmaf(a1, w.x, dl1[4*j4+0]);
            dl1[4*j4+1] = fmaf(a1, w.y, dl1[4*j4+1]);
            dl1[4*j4+2] = fmaf(a1, w.z, dl1[4*j4+2]);
            dl1[4*j4+3] = fmaf(a1, w.w, dl1[4*j4+3]);
        }
    }
    dl0[0] += 1.0f;
    dl1[0] += 1.0f;
}

__device__ __forceinline__ void stage_W(const float* __restrict__ W_in,
                                        const float* __restrict__ b_in,
                                        float4 (*sW4)[57]) {
    for (int idx = threadIdx.x; idx < 8 * 56; idx += 256) {
        int h = idx / 56, r = idx % 56;
        float4 v;
        if (r < 48) {
            int d = r / 8, j4 = r % 8;
            const float* p = W_in + d * 256 + h * 32 + 4 * j4;
            v = make_float4(p[0], p[1], p[2], p[3]);
        } else {
            const float* p = b_in + h * 32 + 4 * (r - 48);
            v = make_float4(p[0], p[1], p[2], p[3]);
        }
        sW4[h][r] = v;
    }
}

// ---------------- K1: chunk totals only (no psi stores) ----------------
// 262144 threads = 4096 waves; launch_bounds(256,3) -> <=168 VGPR, 3 waves/SIMD.
// Chain UNNORMALIZED (positive-rescale equivalence); |p| <= ~1e6 over 4 steps, fp32-safe.
__global__ __launch_bounds__(256, 3) void k_totals(
        const float* __restrict__ x, const float* __restrict__ W_in,
        const float* __restrict__ b_in, float* __restrict__ Tbuf) {
    __shared__ float4 sW4[8][57];
    stage_W(W_in, b_in, sW4);
    __syncthreads();

    int tid = blockIdx.x * 256 + threadIdx.x;
    int c  = tid >> 9;                 // 0..511
    int bh = tid & 511;
    int b = bh >> 3, h = bh & 7;

    float p[32];
#pragma unroll
    for (int k = 0; k < 32; ++k) p[k] = 0.f;
    p[0] = 1.f;

    const float* xrow = x + ((size_t)b * SS + (size_t)c * LCH) * DD;  // 24 floats, 16B-aligned

#pragma unroll
    for (int pr = 0; pr < 2; ++pr) {
        float xc[12];
        const float4* xp = (const float4*)(xrow + pr * 12);
#pragma unroll
        for (int m = 0; m < 3; ++m) {
            float4 t4 = xp[m];
            xc[4*m+0] = t4.x; xc[4*m+1] = t4.y; xc[4*m+2] = t4.z; xc[4*m+3] = t4.w;
        }
        float dl0[32], dl1[32];
        delta_pair(sW4, h, xc, xc + 6, dl0, dl1);

        float o[32];
        gp_cl41(dl0, p, o);   // newer delta LEFT
        gp_cl41(dl1, o, p);
    }

    float inv = rsq(sumsq32(p));
    float* dst = Tbuf + ((size_t)bh * CHUNKS + c) * 32;
#pragma unroll
    for (int k = 0; k < 32; ++k) dst[k] = p[k] * inv;
}

// ---------------- K2: work-efficient pair + Kogge-Stone scan per chain ----------------
// 512 chunks -> 256 pairs; 1 pair GP + 8 KS rounds + 1 odd-fixup GP = 10 GPs/thread.
// Ebuf aliases Tbuf: each thread writes only the slots it itself read (t0 in regs).
__global__ __launch_bounds__(256) void k_scan_totals(
        const float* __restrict__ Tbuf, float* __restrict__ Ebuf) {
    __shared__ float sT[256][33];      // +1 pad
    int chain = blockIdx.x;            // 0..511
    int pp = threadIdx.x;              // pair index 0..255

    float t0[32], t1[32];
    {
        const float* s0 = Tbuf + ((size_t)chain * CHUNKS + 2 * pp) * 32;
#pragma unroll
        for (int k = 0; k < 32; ++k) t0[k] = s0[k];
#pragma unroll
        for (int k = 0; k < 32; ++k) t1[k] = s0[32 + k];
    }

    float v[32];
    {
        float o[32];
        gp_cl41(t1, t0, o);            // pair total: newer (2p+1) LEFT
        float inv = rsq(sumsq32(o));
#pragma unroll
        for (int k = 0; k < 32; ++k) { v[k] = o[k] * inv; sT[pp][k] = v[k]; }
    }
    __syncthreads();

#pragma unroll 1
    for (int off = 1; off < 256; off <<= 1) {
        float w[32];
        bool act = (pp >= off);
        if (act) {
#pragma unroll
            for (int k = 0; k < 32; ++k) w[k] = sT[pp - off][k];
        }
        __syncthreads();
        if (act) {
            float o[32];
            gp_cl41(v, w, o);          // v covers newer range -> left
            float inv = rsq(sumsq32(o));
#pragma unroll
            for (int k = 0; k < 32; ++k) { v[k] = o[k] * inv; sT[pp][k] = v[k]; }
        }
        __syncthreads();
    }

    // exclusive carries: E[2p] = I[p-1] (identity for p=0), E[2p+1] = T[2p] * I[p-1]
    float e0[32];
    if (pp == 0) {
#pragma unroll
        for (int k = 0; k < 32; ++k) e0[k] = (k == 0) ? 1.f : 0.f;
    } else {
#pragma unroll
        for (int k = 0; k < 32; ++k) e0[k] = sT[pp - 1][k];
    }
    float e1[32];
    gp_cl41(t0, e0, e1);               // T[2p] (newer) LEFT
    float inv1 = rsq(sumsq32(e1));

    float* d0 = Ebuf + ((size_t)chain * CHUNKS + 2 * pp) * 32;
#pragma unroll
    for (int k = 0; k < 32; ++k) d0[k] = e0[k];
#pragma unroll
    for (int k = 0; k < 32; ++k) d0[32 + k] = e1[k] * inv1;
}

// ---------------- K3: fused carry-seeded recompute + MFMA projection + norm ----------------
// Block = 128 rows of one b (32 chunks x 8 h = 256 threads). Thread (cl,h): seeds
// p = carry E[bh][c0+cl] (fp32), recomputes its chunk's 4 deltas+GPs, writes bf16
// rows to psiT; 4 waves then project 8 16-row tiles via MFMA. Carries staged
// coalesced into LDS, OVERLAID on psiT (barrier-separated: all carry reads
// complete before any psiT write).
__global__ __launch_bounds__(256) void k_fused(
        const float* __restrict__ x, const float* __restrict__ W_in,
        const float* __restrict__ b_in, const float* __restrict__ Ebuf,
        const float* __restrict__ W_out, const float* __restrict__ b_out,
        float* __restrict__ out) {
    __shared__ ushort_t psiT[128][264];    // 67584 B; first 33 KB doubles as carry stage
    __shared__ float4 sW4[8][57];          // 7296 B
    __shared__ float sX[768];              // 3072 B (128 rows x 6)
    float* carrF = (float*)&psiT[0][0];    // overlay: [h][1032] floats (8*1032*4 = 33024 B)

    int rr0 = blockIdx.x * 128;            // 128 | 2048 -> never straddles b
    int b = rr0 >> 11;
    int s0 = rr0 & 2047;
    int c0 = s0 >> 2;                      // first chunk of this block

    // ---- stage: W, x, carries (all coalesced) ----
    stage_W(W_in, b_in, sW4);
    {
        const float4* xg = (const float4*)(x + ((size_t)b * SS + s0) * DD);  // 768 floats
        for (int idx = threadIdx.x; idx < 192; idx += 256)
            ((float4*)sX)[idx] = xg[idx];
    }
#pragma unroll
    for (int m = 0; m < 32; ++m) {
        int idx = threadIdx.x + m * 256;   // 0..8191
        int hs = idx >> 10;                // 0..7
        int off = idx & 1023;              // cl*32 + comp, contiguous in Ebuf
        carrF[hs * 1032 + off] =
            Ebuf[(((size_t)(b * 8 + hs)) * CHUNKS + c0) * 32 + off];
    }
    __syncthreads();

    int t = threadIdx.x;
    int h = t & 7, cl = t >> 3;            // cl 0..31

    // pull carry to registers (h-stride 1032 dwords -> 2-way bank access, free)
    float p[32];
    {
        const float* cf = carrF + h * 1032 + cl * 32;
#pragma unroll
        for (int k = 0; k < 32; ++k) p[k] = cf[k];
    }
    __syncthreads();                       // all carries read; psiT region now writable

    // ---- carry-seeded chunk recompute, fp32 throughout ----
#pragma unroll
    for (int pr = 0; pr < 2; ++pr) {
        int r0 = cl * 4 + 2 * pr;          // local row of first step in pair
        float xc[12];
        {
            const float* xs = sX + r0 * 6; // 8B-aligned
#pragma unroll
            for (int d = 0; d < 6; ++d) {
                float2 t2 = *(const float2*)(xs + 2 * d);
                xc[2*d] = t2.x; xc[2*d+1] = t2.y;
            }
        }
        float dl0[32], dl1[32];
        delta_pair(sW4, h, xc, xc + 6, dl0, dl1);

        float o[32];
        gp_cl41(dl0, p, o);                // newer delta LEFT; chain seeded with carry
        {
            float inv = rsq(sumsq32(o));
            uint32_t pk[16];
#pragma unroll
            for (int m = 0; m < 16; ++m)
                pk[m] = f2bf_rne(o[2*m] * inv) | (f2bf_rne(o[2*m+1] * inv) << 16);
            uint4* dst = (uint4*)&psiT[r0][h * 32];
#pragma unroll
            for (int m = 0; m < 4; ++m)
                dst[m] = make_uint4(pk[4*m], pk[4*m+1], pk[4*m+2], pk[4*m+3]);
        }
        gp_cl41(dl1, o, p);
        {
            float inv = rsq(sumsq32(p));
            uint32_t pk[16];
#pragma unroll
            for (int m = 0; m < 16; ++m)
                pk[m] = f2bf_rne(p[2*m] * inv) | (f2bf_rne(p[2*m+1] * inv) << 16);
            uint4* dst = (uint4*)&psiT[r0 + 1][h * 32];
#pragma unroll
            for (int m = 0; m < 4; ++m)
                dst[m] = make_uint4(pk[4*m], pk[4*m+1], pk[4*m+2], pk[4*m+3]);
        }
    }

    // ---- B-fragments for projection (loaded late to cap live range) ----
    int lane = t & 63;
    int wv = t >> 6;
    int q = lane >> 4;
    int n0 = lane & 15;
    bf16x8 Bf[2][8];
#pragma unroll
    for (int nt = 0; nt < 2; ++nt)
#pragma unroll
        for (int kk = 0; kk < 8; ++kk) {
            union { ushort_t u[8]; bf16x8 v; } tmp;
#pragma unroll
            for (int j = 0; j < 8; ++j)
                tmp.u[j] = (ushort_t)f2bf_rne(W_out[(kk * 32 + q * 8 + j) * 32 + nt * 16 + n0]);
            Bf[nt][kk] = tmp.v;
        }
    float bn0 = b_out[n0], bn1 = b_out[16 + n0];

    __syncthreads();                       // psiT complete

    // ---- projection: 8 tiles of 16 rows; wave wv handles tiles 2wv, 2wv+1 ----
#pragma unroll
    for (int tt = 0; tt < 2; ++tt) {
        int tl = wv * 2 + tt;
        int r16 = tl * 16;

        f32x4 acc0 = {0.f, 0.f, 0.f, 0.f};
        f32x4 acc1 = {0.f, 0.f, 0.f, 0.f};
#pragma unroll
        for (int kk = 0; kk < 8; ++kk) {
            // A-frag: A[m=lane&15][k=kk*32+q*8+j]
            bf16x8 af = *(const bf16x8*)&psiT[r16 + n0][kk * 32 + q * 8];
            acc0 = __builtin_amdgcn_mfma_f32_16x16x32_bf16(af, Bf[0][kk], acc0, 0, 0, 0);
            acc1 = __builtin_amdgcn_mfma_f32_16x16x32_bf16(af, Bf[1][kk], acc1, 0, 0, 0);
        }

        float c0v[4], c1v[4], ss[4];
#pragma unroll
        for (int i = 0; i < 4; ++i) {
            c0v[i] = acc0[i] + bn0;
            c1v[i] = acc1[i] + bn1;
            ss[i] = c0v[i] * c0v[i] + c1v[i] * c1v[i];
        }
#pragma unroll
        for (int m = 1; m < 16; m <<= 1) {
#pragma unroll
            for (int i = 0; i < 4; ++i) ss[i] += __shfl_xor(ss[i], m);
        }
#pragma unroll
        for (int i = 0; i < 4; ++i) {
            float inv = rsq(ss[i]);
            int row = rr0 + r16 + q * 4 + i;
            out[(size_t)row * 32 + n0]      = c0v[i] * inv;
            out[(size_t)row * 32 + 16 + n0] = c1v[i] * inv;
        }
    }
}

// ---------------- launcher ----------------
extern "C" void kernel_launch(void* const* d_in, const int* in_sizes, int n_in,
                              void* d_out, int out_size, void* d_ws, size_t ws_size,
                              hipStream_t stream) {
    const float* x     = (const float*)d_in[0];
    const float* W_in  = (const float*)d_in[1];
    const float* b_in  = (const float*)d_in[2];
    const float* W_out = (const float*)d_in[3];
    const float* b_out = (const float*)d_in[4];
    float* out = (float*)d_out;

    float* Tbuf = (float*)d_ws;            // 512*512*32*4 = 32 MB fp32 (<= 80 MB ceiling)
    float* Ebuf = Tbuf;                    // aliased (safe, see K2)

    k_totals     <<<1024, 256, 0, stream>>>(x, W_in, b_in, Tbuf);
    k_scan_totals<<< 512, 256, 0, stream>>>(Tbuf, Ebuf);
    k_fused      <<<1024, 256, 0, stream>>>(x, W_in, b_in, Ebuf, W_out, b_out, out);
}

// Round 9
// 244.978 us; speedup vs baseline: 1.7298x; 1.7298x over previous
//
#include <hip/hip_runtime.h>
#include <hip/hip_bf16.h>
#include <stdint.h>

// Problem constants (from reference setup_inputs)
#define BB 64
#define SS 2048
#define DD 6
#define HH 8
#define NCH 512           // chains = B*H
#define CHUNKS 512        // chunks per chain
#define LCH 4             // steps per chunk = SS/CHUNKS
// WORKSPACE CEILING: 80 MB (round 6 at 96 MB OOB-stomped). This round uses 32 MB.
// REGISTER RULE (round 8): GP live set needs ~130+ VGPRs; __launch_bounds__ min-waves
// hints beyond 2/SIMD force scratch spills (VGPR 84, 640 MB spill traffic, 4x slower).

typedef unsigned short ushort_t;
typedef __attribute__((ext_vector_type(8))) __bf16 bf16x8;
typedef __attribute__((ext_vector_type(4))) float f32x4;

// ---------------- compile-time Cayley sign table (Cl(4,1)) ----------------
struct SignTab { float s[32][32]; };

constexpr int popc5_c(unsigned v) {
    int c = 0;
    for (int i = 0; i < 5; ++i) c += (v >> i) & 1u;
    return c;
}

constexpr SignTab make_signs() {
    SignTab t{};
    for (int a = 0; a < 32; ++a) {
        for (int b = 0; b < 32; ++b) {
            int cnt = 0;
            unsigned aa = ((unsigned)a) >> 1;
            while (aa) { cnt += popc5_c(aa & (unsigned)b); aa >>= 1; }
            if ((a & b) & 16) cnt += 1;   // metric: e5^2 = -1 (bit 4)
            t.s[a][b] = (cnt & 1) ? -1.0f : 1.0f;
        }
    }
    return t;
}

constexpr SignTab SGN = make_signs();

// out = a * b  (geometric product, a is LEFT operand: out_k = sum_i s(i,i^k) a_i b_{i^k})
__device__ __forceinline__ void gp_cl41(const float* __restrict__ a,
                                        const float* __restrict__ b,
                                        float* __restrict__ o) {
#pragma unroll
    for (int k = 0; k < 32; ++k) o[k] = 0.0f;
#pragma unroll
    for (int i = 0; i < 32; ++i) {
#pragma unroll
        for (int k = 0; k < 32; ++k) {
            o[k] = fmaf(SGN.s[i][i ^ k] * a[i], b[i ^ k], o[k]);
        }
    }
}

__device__ __forceinline__ float sumsq32(const float* v) {
    float n0 = 0.f, n1 = 0.f, n2 = 0.f, n3 = 0.f;
#pragma unroll
    for (int k = 0; k < 32; k += 4) {
        n0 = fmaf(v[k+0], v[k+0], n0);
        n1 = fmaf(v[k+1], v[k+1], n1);
        n2 = fmaf(v[k+2], v[k+2], n2);
        n3 = fmaf(v[k+3], v[k+3], n3);
    }
    return (n0 + n1) + (n2 + n3);
}

__device__ __forceinline__ float rsq(float n) {
    return __builtin_amdgcn_rsqf(n);   // v_rsq_f32, scale-equivalent
}

__device__ __forceinline__ uint32_t f2bf_rne(float f) {
    uint32_t u = __float_as_uint(f);
    return (u + 0x7FFFu + ((u >> 16) & 1u)) >> 16;
}

// delta for two consecutive steps from one W sweep (sW4 layout: [h][d*8+j4]=W, [h][48..55]=bias)
__device__ __forceinline__ void delta_pair(const float4 (*sW4)[57], int h,
                                           const float* x0, const float* x1,
                                           float* dl0, float* dl1) {
#pragma unroll
    for (int j4 = 0; j4 < 8; ++j4) {
        float4 bv = sW4[h][48 + j4];
        dl0[4*j4+0] = bv.x; dl0[4*j4+1] = bv.y; dl0[4*j4+2] = bv.z; dl0[4*j4+3] = bv.w;
        dl1[4*j4+0] = bv.x; dl1[4*j4+1] = bv.y; dl1[4*j4+2] = bv.z; dl1[4*j4+3] = bv.w;
    }
#pragma unroll
    for (int d = 0; d < 6; ++d) {
        float a0 = x0[d], a1 = x1[d];
#pragma unroll
        for (int j4 = 0; j4 < 8; ++j4) {
            float4 w = sW4[h][d * 8 + j4];   // one LDS read serves both steps
            dl0[4*j4+0] = fmaf(a0, w.x, dl0[4*j4+0]);
            dl0[4*j4+1] = fmaf(a0, w.y, dl0[4*j4+1]);
            dl0[4*j4+2] = fmaf(a0, w.z, dl0[4*j4+2]);
            dl0[4*j4+3] = fmaf(a0, w.w, dl0[4*j4+3]);
            dl1[4*j4+0] = fmaf(a1, w.x, dl1[4*j4+0]);
            dl1[4*j4+1] = fmaf(a1, w.y, dl1[4*j4+1]);
            dl1[4*j4+2] = fmaf(a1, w.z, dl1[4*j4+2]);
            dl1[4*j4+3] = fmaf(a1, w.w, dl1[4*j4+3]);
        }
    }
    dl0[0] += 1.0f;
    dl1[0] += 1.0f;
}

__device__ __forceinline__ void stage_W(const float* __restrict__ W_in,
                                        const float* __restrict__ b_in,
                                        float4 (*sW4)[57]) {
    for (int idx = threadIdx.x; idx < 8 * 56; idx += 256) {
        int h = idx / 56, r = idx % 56;
        float4 v;
        if (r < 48) {
            int d = r / 8, j4 = r % 8;
            const float* p = W_in + d * 256 + h * 32 + 4 * j4;
            v = make_float4(p[0], p[1], p[2], p[3]);
        } else {
            const float* p = b_in + h * 32 + 4 * (r - 48);
            v = make_float4(p[0], p[1], p[2], p[3]);
        }
        sW4[h][r] = v;
    }
}

// ---------------- K1: chunk totals only (no psi stores) ----------------
// 262144 threads = 4096 waves. NO min-waves bound: GP live set needs ~256 VGPR
// (2 waves/SIMD); forcing 3 spills to scratch (round 8: 640 MB traffic, 4x slower).
// Chain UNNORMALIZED (positive-rescale equivalence); |p| <= ~1e6 over 4 steps, fp32-safe.
__global__ __launch_bounds__(256) void k_totals(
        const float* __restrict__ x, const float* __restrict__ W_in,
        const float* __restrict__ b_in, float* __restrict__ Tbuf) {
    __shared__ float4 sW4[8][57];
    stage_W(W_in, b_in, sW4);
    __syncthreads();

    int tid = blockIdx.x * 256 + threadIdx.x;
    int c  = tid >> 9;                 // 0..511
    int bh = tid & 511;
    int b = bh >> 3, h = bh & 7;

    float p[32];
#pragma unroll
    for (int k = 0; k < 32; ++k) p[k] = 0.f;
    p[0] = 1.f;

    const float* xrow = x + ((size_t)b * SS + (size_t)c * LCH) * DD;  // 24 floats, 16B-aligned

#pragma unroll
    for (int pr = 0; pr < 2; ++pr) {
        float xc[12];
        const float4* xp = (const float4*)(xrow + pr * 12);
#pragma unroll
        for (int m = 0; m < 3; ++m) {
            float4 t4 = xp[m];
            xc[4*m+0] = t4.x; xc[4*m+1] = t4.y; xc[4*m+2] = t4.z; xc[4*m+3] = t4.w;
        }
        float dl0[32], dl1[32];
        delta_pair(sW4, h, xc, xc + 6, dl0, dl1);

        float o[32];
        gp_cl41(dl0, p, o);   // newer delta LEFT
        gp_cl41(dl1, o, p);
    }

    float inv = rsq(sumsq32(p));
    float* dst = Tbuf + ((size_t)bh * CHUNKS + c) * 32;
#pragma unroll
    for (int k = 0; k < 32; ++k) dst[k] = p[k] * inv;
}

// ---------------- K2: work-efficient pair + Kogge-Stone scan per chain ----------------
// 512 chunks -> 256 pairs; 1 pair GP + 8 KS rounds + 1 odd-fixup GP = 10 GPs/thread.
// Ebuf aliases Tbuf: each thread writes only the slots it itself read (t0 in regs).
__global__ __launch_bounds__(256) void k_scan_totals(
        const float* __restrict__ Tbuf, float* __restrict__ Ebuf) {
    __shared__ float sT[256][33];      // +1 pad
    int chain = blockIdx.x;            // 0..511
    int pp = threadIdx.x;              // pair index 0..255

    float t0[32], t1[32];
    {
        const float* s0 = Tbuf + ((size_t)chain * CHUNKS + 2 * pp) * 32;
#pragma unroll
        for (int k = 0; k < 32; ++k) t0[k] = s0[k];
#pragma unroll
        for (int k = 0; k < 32; ++k) t1[k] = s0[32 + k];
    }

    float v[32];
    {
        float o[32];
        gp_cl41(t1, t0, o);            // pair total: newer (2p+1) LEFT
        float inv = rsq(sumsq32(o));
#pragma unroll
        for (int k = 0; k < 32; ++k) { v[k] = o[k] * inv; sT[pp][k] = v[k]; }
    }
    __syncthreads();

#pragma unroll 1
    for (int off = 1; off < 256; off <<= 1) {
        float w[32];
        bool act = (pp >= off);
        if (act) {
#pragma unroll
            for (int k = 0; k < 32; ++k) w[k] = sT[pp - off][k];
        }
        __syncthreads();
        if (act) {
            float o[32];
            gp_cl41(v, w, o);          // v covers newer range -> left
            float inv = rsq(sumsq32(o));
#pragma unroll
            for (int k = 0; k < 32; ++k) { v[k] = o[k] * inv; sT[pp][k] = v[k]; }
        }
        __syncthreads();
    }

    // exclusive carries: E[2p] = I[p-1] (identity for p=0), E[2p+1] = T[2p] * I[p-1]
    float e0[32];
    if (pp == 0) {
#pragma unroll
        for (int k = 0; k < 32; ++k) e0[k] = (k == 0) ? 1.f : 0.f;
    } else {
#pragma unroll
        for (int k = 0; k < 32; ++k) e0[k] = sT[pp - 1][k];
    }
    float e1[32];
    gp_cl41(t0, e0, e1);               // T[2p] (newer) LEFT
    float inv1 = rsq(sumsq32(e1));

    float* d0 = Ebuf + ((size_t)chain * CHUNKS + 2 * pp) * 32;
#pragma unroll
    for (int k = 0; k < 32; ++k) d0[k] = e0[k];
#pragma unroll
    for (int k = 0; k < 32; ++k) d0[32 + k] = e1[k] * inv1;
}

// ---------------- K3: fused carry-seeded recompute + MFMA projection + norm ----------------
// Block = 128 rows of one b (32 chunks x 8 h = 256 threads). Thread (cl,h): seeds
// p = carry E[bh][c0+cl] (fp32), recomputes its chunk's 4 deltas+GPs, writes bf16
// rows to psiT; 4 waves then project 8 16-row tiles via MFMA. Carries staged
// coalesced into LDS, OVERLAID on psiT (barrier-separated).
__global__ __launch_bounds__(256) void k_fused(
        const float* __restrict__ x, const float* __restrict__ W_in,
        const float* __restrict__ b_in, const float* __restrict__ Ebuf,
        const float* __restrict__ W_out, const float* __restrict__ b_out,
        float* __restrict__ out) {
    __shared__ ushort_t psiT[128][264];    // 67584 B; first 33 KB doubles as carry stage
    __shared__ float4 sW4[8][57];          // 7296 B
    __shared__ float sX[768];              // 3072 B (128 rows x 6)
    float* carrF = (float*)&psiT[0][0];    // overlay: [h][1032] floats (8*1032*4 = 33024 B)

    int rr0 = blockIdx.x * 128;            // 128 | 2048 -> never straddles b
    int b = rr0 >> 11;
    int s0 = rr0 & 2047;
    int c0 = s0 >> 2;                      // first chunk of this block

    // ---- stage: W, x, carries (all coalesced) ----
    stage_W(W_in, b_in, sW4);
    {
        const float4* xg = (const float4*)(x + ((size_t)b * SS + s0) * DD);  // 768 floats
        for (int idx = threadIdx.x; idx < 192; idx += 256)
            ((float4*)sX)[idx] = xg[idx];
    }
#pragma unroll
    for (int m = 0; m < 32; ++m) {
        int idx = threadIdx.x + m * 256;   // 0..8191
        int hs = idx >> 10;                // 0..7
        int off = idx & 1023;              // cl*32 + comp, contiguous in Ebuf
        carrF[hs * 1032 + off] =
            Ebuf[(((size_t)(b * 8 + hs)) * CHUNKS + c0) * 32 + off];
    }
    __syncthreads();

    int t = threadIdx.x;
    int h = t & 7, cl = t >> 3;            // cl 0..31

    // pull carry to registers
    float p[32];
    {
        const float* cf = carrF + h * 1032 + cl * 32;
#pragma unroll
        for (int k = 0; k < 32; ++k) p[k] = cf[k];
    }
    __syncthreads();                       // all carries read; psiT region now writable

    // ---- carry-seeded chunk recompute, fp32 throughout ----
#pragma unroll
    for (int pr = 0; pr < 2; ++pr) {
        int r0 = cl * 4 + 2 * pr;          // local row of first step in pair
        float xc[12];
        {
            const float* xs = sX + r0 * 6; // 8B-aligned
#pragma unroll
            for (int d = 0; d < 6; ++d) {
                float2 t2 = *(const float2*)(xs + 2 * d);
                xc[2*d] = t2.x; xc[2*d+1] = t2.y;
            }
        }
        float dl0[32], dl1[32];
        delta_pair(sW4, h, xc, xc + 6, dl0, dl1);

        float o[32];
        gp_cl41(dl0, p, o);                // newer delta LEFT; chain seeded with carry
        {
            float inv = rsq(sumsq32(o));
            uint32_t pk[16];
#pragma unroll
            for (int m = 0; m < 16; ++m)
                pk[m] = f2bf_rne(o[2*m] * inv) | (f2bf_rne(o[2*m+1] * inv) << 16);
            uint4* dst = (uint4*)&psiT[r0][h * 32];
#pragma unroll
            for (int m = 0; m < 4; ++m)
                dst[m] = make_uint4(pk[4*m], pk[4*m+1], pk[4*m+2], pk[4*m+3]);
        }
        gp_cl41(dl1, o, p);
        {
            float inv = rsq(sumsq32(p));
            uint32_t pk[16];
#pragma unroll
            for (int m = 0; m < 16; ++m)
                pk[m] = f2bf_rne(p[2*m] * inv) | (f2bf_rne(p[2*m+1] * inv) << 16);
            uint4* dst = (uint4*)&psiT[r0 + 1][h * 32];
#pragma unroll
            for (int m = 0; m < 4; ++m)
                dst[m] = make_uint4(pk[4*m], pk[4*m+1], pk[4*m+2], pk[4*m+3]);
        }
    }

    // ---- B-fragments for projection (loaded late to cap live range) ----
    int lane = t & 63;
    int wv = t >> 6;
    int q = lane >> 4;
    int n0 = lane & 15;
    bf16x8 Bf[2][8];
#pragma unroll
    for (int nt = 0; nt < 2; ++nt)
#pragma unroll
        for (int kk = 0; kk < 8; ++kk) {
            union { ushort_t u[8]; bf16x8 v; } tmp;
#pragma unroll
            for (int j = 0; j < 8; ++j)
                tmp.u[j] = (ushort_t)f2bf_rne(W_out[(kk * 32 + q * 8 + j) * 32 + nt * 16 + n0]);
            Bf[nt][kk] = tmp.v;
        }
    float bn0 = b_out[n0], bn1 = b_out[16 + n0];

    __syncthreads();                       // psiT complete

    // ---- projection: 8 tiles of 16 rows; wave wv handles tiles 2wv, 2wv+1 ----
#pragma unroll
    for (int tt = 0; tt < 2; ++tt) {
        int tl = wv * 2 + tt;
        int r16 = tl * 16;

        f32x4 acc0 = {0.f, 0.f, 0.f, 0.f};
        f32x4 acc1 = {0.f, 0.f, 0.f, 0.f};
#pragma unroll
        for (int kk = 0; kk < 8; ++kk) {
            // A-frag: A[m=lane&15][k=kk*32+q*8+j]
            bf16x8 af = *(const bf16x8*)&psiT[r16 + n0][kk * 32 + q * 8];
            acc0 = __builtin_amdgcn_mfma_f32_16x16x32_bf16(af, Bf[0][kk], acc0, 0, 0, 0);
            acc1 = __builtin_amdgcn_mfma_f32_16x16x32_bf16(af, Bf[1][kk], acc1, 0, 0, 0);
        }

        float c0v[4], c1v[4], ss[4];
#pragma unroll
        for (int i = 0; i < 4; ++i) {
            c0v[i] = acc0[i] + bn0;
            c1v[i] = acc1[i] + bn1;
            ss[i] = c0v[i] * c0v[i] + c1v[i] * c1v[i];
        }
#pragma unroll
        for (int m = 1; m < 16; m <<= 1) {
#pragma unroll
            for (int i = 0; i < 4; ++i) ss[i] += __shfl_xor(ss[i], m);
        }
#pragma unroll
        for (int i = 0; i < 4; ++i) {
            float inv = rsq(ss[i]);
            int row = rr0 + r16 + q * 4 + i;
            out[(size_t)row * 32 + n0]      = c0v[i] * inv;
            out[(size_t)row * 32 + 16 + n0] = c1v[i] * inv;
        }
    }
}

// ---------------- launcher ----------------
extern "C" void kernel_launch(void* const* d_in, const int* in_sizes, int n_in,
                              void* d_out, int out_size, void* d_ws, size_t ws_size,
                              hipStream_t stream) {
    const float* x     = (const float*)d_in[0];
    const float* W_in  = (const float*)d_in[1];
    const float* b_in  = (const float*)d_in[2];
    const float* W_out = (const float*)d_in[3];
    const float* b_out = (const float*)d_in[4];
    float* out = (float*)d_out;

    float* Tbuf = (float*)d_ws;            // 512*512*32*4 = 32 MB fp32 (<= 80 MB ceiling)
    float* Ebuf = Tbuf;                    // aliased (safe, see K2)

    k_totals     <<<1024, 256, 0, stream>>>(x, W_in, b_in, Tbuf);
    k_scan_totals<<< 512, 256, 0, stream>>>(Tbuf, Ebuf);
    k_fused      <<<1024, 256, 0, stream>>>(x, W_in, b_in, Ebuf, W_out, b_out, out);
}